// Round 1
// baseline (818.598 us; speedup 1.0000x reference)
//
#include <hip/hip_runtime.h>
#include <stdint.h>

#define BATCH 8
#define NN 262144
#define K_PRE 6000
#define NPROP 1000
#define NMS_THR 0.7f
#define CAND_CAP 8192
#define PREFIX 2048
#define NB1 16384
#define NB2 4096

// workspace layout (bytes)
#define HIST1_OFF 0                                   // BATCH*NB1*4 = 524288
#define HIST2_OFF (HIST1_OFF + BATCH*NB1*4)           // + BATCH*NB2*4 = 131072
#define META_OFF  (HIST2_OFF + BATCH*NB2*4)           // 64 u32 = 256 B
#define CAND_OFF  (META_OFF + 256)
#define BOXES_OFF (CAND_OFF + BATCH*CAND_CAP*8)       // BATCH*K_PRE*16
#define MASK_OFF  (BOXES_OFF + BATCH*K_PRE*16)        // BATCH*PREFIX*64*4 = 4 MB
#define KIDX_OFF  (MASK_OFF + (size_t)BATCH*PREFIX*64*4)
#define WS_NEED   (KIDX_OFF + BATCH*NPROP*4)

__device__ __forceinline__ uint32_t fkey(float f) {
    uint32_t b = __float_as_uint(f);
    return b ^ (uint32_t)(((int32_t)b >> 31) | 0x80000000u);
}

__global__ void k_zero(uint32_t* h) {
    const int i = blockIdx.x * 256 + threadIdx.x;
    if (i < BATCH * (NB1 + NB2)) h[i] = 0;
}

__global__ __launch_bounds__(256) void k_hist(const float2* __restrict__ probs,
                                              uint32_t* __restrict__ hist) {
    __shared__ uint32_t h[NB1];
    for (int i = threadIdx.x; i < NB1; i += 256) h[i] = 0;
    __syncthreads();
    const int b = blockIdx.x >> 3;
    const int s = blockIdx.x & 7;
    const float2* p = probs + (size_t)b * NN + (size_t)s * (NN / 8);
    for (int i = threadIdx.x; i < NN / 8; i += 256) {
        atomicAdd(&h[fkey(p[i].y) >> 18], 1u);
    }
    __syncthreads();
    uint32_t* gh = hist + (size_t)b * NB1;
    for (int i = threadIdx.x; i < NB1; i += 256)
        if (h[i]) atomicAdd(&gh[i], h[i]);
}

__global__ __launch_bounds__(256) void k_thresh(const uint32_t* __restrict__ hist,
                                                uint32_t* meta) {
    const int b = blockIdx.x;
    const uint32_t* gh = hist + (size_t)b * NB1;
    __shared__ uint32_t part[256];
    const int t = threadIdx.x;
    uint32_t s = 0;
    const int hi = NB1 - 64 * t;
    for (int i = hi - 64; i < hi; ++i) s += gh[i];
    part[t] = s;
    __syncthreads();
    if (t == 0) {
        uint32_t cum = 0;
        int strip = 0;
        for (; strip < 256; ++strip) {
            if (cum + part[strip] >= (uint32_t)K_PRE) break;
            cum += part[strip];
        }
        int t1 = 0;
        if (strip < 256) {
            const int top = NB1 - 64 * strip;
            int i = top - 1;
            for (; i >= top - 64; --i) {
                const uint32_t c = gh[i];
                if (cum + c >= (uint32_t)K_PRE) break;
                cum += c;
            }
            if (i < top - 64) i = top - 64;
            t1 = i;
        }
        meta[24 + b] = (uint32_t)t1;
        meta[32 + b] = cum;  // count strictly above bucket t1
    }
}

__global__ __launch_bounds__(256) void k_hist2(const float2* __restrict__ probs,
                                               const uint32_t* __restrict__ meta,
                                               uint32_t* __restrict__ hist2) {
    __shared__ uint32_t h[NB2];
    for (int i = threadIdx.x; i < NB2; i += 256) h[i] = 0;
    __syncthreads();
    const int b = blockIdx.x >> 3;
    const int s = blockIdx.x & 7;
    const uint32_t t1 = meta[24 + b];
    const float2* p = probs + (size_t)b * NN + (size_t)s * (NN / 8);
    for (int i = threadIdx.x; i < NN / 8; i += 256) {
        const uint32_t u = fkey(p[i].y);
        if ((u >> 18) == t1) atomicAdd(&h[(u >> 6) & 0xFFFu], 1u);
    }
    __syncthreads();
    uint32_t* gh = hist2 + (size_t)b * NB2;
    for (int i = threadIdx.x; i < NB2; i += 256)
        if (h[i]) atomicAdd(&gh[i], h[i]);
}

__global__ __launch_bounds__(256) void k_thresh2(const uint32_t* __restrict__ hist2,
                                                 uint32_t* meta) {
    const int b = blockIdx.x;
    const uint32_t* gh = hist2 + (size_t)b * NB2;
    __shared__ uint32_t part[256];
    const int t = threadIdx.x;
    uint32_t s = 0;
    const int hi = NB2 - 16 * t;
    for (int i = hi - 16; i < hi; ++i) s += gh[i];
    part[t] = s;
    __syncthreads();
    if (t == 0) {
        const uint32_t t1 = meta[24 + b];
        uint32_t cum = meta[32 + b];
        int strip = 0;
        for (; strip < 256; ++strip) {
            if (cum + part[strip] >= (uint32_t)K_PRE) break;
            cum += part[strip];
        }
        int sub = 0;
        if (strip < 256) {
            const int top = NB2 - 16 * strip;
            int i = top - 1;
            for (; i >= top - 16; --i) {
                const uint32_t c = gh[i];
                if (cum + c >= (uint32_t)K_PRE) break;
                cum += c;
            }
            if (i < top - 16) i = top - 16;
            sub = i;
        }
        meta[b] = (t1 << 18) | ((uint32_t)sub << 6);
        meta[8 + b] = 0;   // cnt
        meta[16 + b] = 0;  // kept
    }
}

__global__ __launch_bounds__(256) void k_compact(const float2* __restrict__ probs,
                                                 const uint32_t* __restrict__ meta,
                                                 uint32_t* cnt, uint64_t* __restrict__ cand) {
    const int b = blockIdx.x >> 3;
    const int s = blockIdx.x & 7;
    const uint32_t T = meta[b];
    const float2* p = probs + (size_t)b * NN + (size_t)s * (NN / 8);
    const uint32_t base_n = (uint32_t)s * (NN / 8);
    const int lane = threadIdx.x & 63;
    for (int i = threadIdx.x; i < NN / 8; i += 256) {
        const uint32_t u = fkey(p[i].y);
        const bool pass = (u >= T);
        const unsigned long long m = __ballot(pass);
        if (pass) {
            const uint32_t pre = (uint32_t)__popcll(m & ((1ull << lane) - 1ull));
            const int leader = (int)(__ffsll((long long)m) - 1);
            uint32_t base = 0;
            if (lane == leader) base = atomicAdd(&cnt[b], (uint32_t)__popcll(m));
            base = __shfl(base, leader);
            const uint32_t pos = base + pre;
            if (pos < CAND_CAP) {
                const uint32_t n = base_n + (uint32_t)i;
                cand[(size_t)b * CAND_CAP + pos] = ((uint64_t)u << 32) | (uint32_t)(~n);
            }
        }
    }
}

__global__ __launch_bounds__(1024) void k_sortdecode(const uint64_t* __restrict__ cand,
        const uint32_t* __restrict__ meta,
        const float4* __restrict__ bbox, const float4* __restrict__ anch,
        float4* __restrict__ boxes) {
    __shared__ uint64_t key[CAND_CAP];
    const int b = blockIdx.x;
    const uint32_t m = min(meta[8 + b], (uint32_t)CAND_CAP);
    const uint64_t* c = cand + (size_t)b * CAND_CAP;
    for (int i = threadIdx.x; i < CAND_CAP; i += 1024)
        key[i] = (i < (int)m) ? c[i] : 0ull;
    __syncthreads();
    for (int k = 2; k <= CAND_CAP; k <<= 1) {
        for (int j = k >> 1; j > 0; j >>= 1) {
            for (int t = threadIdx.x; t < CAND_CAP / 2; t += 1024) {
                const int i = ((t & ~(j - 1)) << 1) | (t & (j - 1));
                const int p = i | j;
                const uint64_t a = key[i], bb = key[p];
                const bool up = ((i & k) == 0);
                if ((a < bb) == up) { key[i] = bb; key[p] = a; }
            }
            __syncthreads();
        }
    }
    for (int r = threadIdx.x; r < K_PRE; r += 1024) {
        const uint32_t n = ~((uint32_t)key[r]);
        const float4 a = anch[(size_t)b * NN + n];
        const float4 d = bbox[(size_t)b * NN + n];
        float h = a.z - a.x, w = a.w - a.y;
        const float cy0 = a.x + 0.5f * h + d.x * 0.1f * h;
        const float cx0 = a.y + 0.5f * w + d.y * 0.1f * w;
        h = h * expf(d.z * 0.2f);
        w = w * expf(d.w * 0.2f);
        float4 o;
        o.x = fminf(fmaxf(cy0 - 0.5f * h, 0.0f), 1.0f);
        o.y = fminf(fmaxf(cx0 - 0.5f * w, 0.0f), 1.0f);
        o.z = fminf(fmaxf(cy0 + 0.5f * h, 0.0f), 1.0f);
        o.w = fminf(fmaxf(cx0 + 0.5f * w, 0.0f), 1.0f);
        boxes[(size_t)b * K_PRE + r] = o;
    }
}

__global__ __launch_bounds__(256) void k_matrix(const float4* __restrict__ boxes,
                                                uint32_t* __restrict__ mask) {
    const int blk = blockIdx.x;
    const int b = blk >> 10;
    const int tile = blk & 1023;
    const int ti = tile >> 5, tj = tile & 31;
    __shared__ float4 rb[64], cb[64];
    __shared__ uint32_t wbits[128];
    const float4* bx = boxes + (size_t)b * K_PRE;
    const int t = threadIdx.x;
    if (t < 64) rb[t] = bx[ti * 64 + t];
    else if (t < 128) cb[t - 64] = bx[tj * 64 + (t - 64)];
    if (t < 128) wbits[t] = 0;
    __syncthreads();
    const int r = t >> 2;
    const int cq = t & 3;
    const float4 a = rb[r];
    const float areaA = (a.z - a.x) * (a.w - a.y);
    uint32_t bits = 0;
#pragma unroll
    for (int jj = 0; jj < 16; ++jj) {
        const float4 cc = cb[cq * 16 + jj];
        const float yy1 = fmaxf(a.x, cc.x), xx1 = fmaxf(a.y, cc.y);
        const float yy2 = fminf(a.z, cc.z), xx2 = fminf(a.w, cc.w);
        const float inter = fmaxf(yy2 - yy1, 0.0f) * fmaxf(xx2 - xx1, 0.0f);
        const float areaC = (cc.z - cc.x) * (cc.w - cc.y);
        const float uni = fmaxf(areaA + areaC - inter, 1e-8f);
        if (inter / uni > NMS_THR) bits |= (1u << jj);
    }
    atomicOr(&wbits[r * 2 + (cq >> 1)], bits << ((cq & 1) * 16));
    __syncthreads();
    if (t < 128) {
        const int rr = t >> 1, ww = t & 1;
        mask[((size_t)b * PREFIX + ti * 64 + rr) * 64 + tj * 2 + ww] = wbits[rr * 2 + ww];
    }
}

__global__ __launch_bounds__(64) void k_greedy(const uint32_t* __restrict__ mask,
                                               uint32_t* meta, uint32_t* __restrict__ kept_idx) {
    const int b = blockIdx.x;
    const int lane = threadIdx.x;
    __shared__ uint32_t klist[NPROP];
    const uint32_t* mrow = mask + (size_t)b * PREFIX * 64;
    uint32_t buf[32];
#pragma unroll
    for (int q = 0; q < 32; ++q) buf[q] = mrow[(size_t)q * 64 + lane];
    uint32_t supp = 0;
    uint32_t kept = 0;
    for (int w = 0; w < PREFIX / 32; ++w) {
        uint32_t sw = __builtin_amdgcn_readlane(supp, w);
#pragma unroll
        for (int q = 0; q < 32; ++q) {
            const int i = w * 32 + q;
            const uint32_t rcur = buf[q];
            if (i + 32 < PREFIX) buf[q] = mrow[(size_t)(i + 32) * 64 + lane];
            const bool take = (kept < NPROP) && !((sw >> q) & 1u);
            if (take) {
                if (lane == 0) klist[kept] = (uint32_t)i;
                supp |= rcur;
                sw |= __builtin_amdgcn_readlane(rcur, w);
                ++kept;
            }
        }
        if (kept >= NPROP) break;
    }
    if (lane == 0) meta[16 + b] = kept;
    __syncthreads();
    for (uint32_t k = lane; k < kept; k += 64)
        kept_idx[(size_t)b * NPROP + k] = klist[k];
}

__global__ __launch_bounds__(1024) void k_finish(const float4* __restrict__ boxes,
        uint32_t* meta, uint32_t* kept_idx, float4* __restrict__ out) {
    const int b = blockIdx.x;
    const float4* bx = boxes + (size_t)b * K_PRE;
    __shared__ float4 kb[NPROP];
    __shared__ uint32_t sflag;
    uint32_t kept = meta[16 + b];
    if (kept < NPROP) {
        for (uint32_t k = threadIdx.x; k < kept; k += 1024)
            kb[k] = bx[kept_idx[(size_t)b * NPROP + k]];
        __syncthreads();
        for (int i = PREFIX; i < K_PRE && kept < NPROP; ++i) {
            if (threadIdx.x == 0) sflag = 0;
            __syncthreads();
            const float4 c = bx[i];
            const float areaC = (c.z - c.x) * (c.w - c.y);
            bool sup = false;
            for (uint32_t k = threadIdx.x; k < kept; k += 1024) {
                const float4 a = kb[k];
                const float yy1 = fmaxf(c.x, a.x), xx1 = fmaxf(c.y, a.y);
                const float yy2 = fminf(c.z, a.z), xx2 = fminf(c.w, a.w);
                const float inter = fmaxf(yy2 - yy1, 0.0f) * fmaxf(xx2 - xx1, 0.0f);
                const float areaA = (a.z - a.x) * (a.w - a.y);
                const float uni = fmaxf(areaC + areaA - inter, 1e-8f);
                if (inter / uni > NMS_THR) { sup = true; break; }
            }
            if (sup) atomicOr(&sflag, 1u);
            __syncthreads();
            if (sflag == 0) {
                if (threadIdx.x == 0) {
                    kept_idx[(size_t)b * NPROP + kept] = (uint32_t)i;
                    kb[kept] = c;
                }
                ++kept;
            }
            __syncthreads();
        }
        if (threadIdx.x == 0) meta[16 + b] = kept;
    }
    __syncthreads();
    for (uint32_t k = threadIdx.x; k < NPROP; k += 1024) {
        float4 v = make_float4(0.f, 0.f, 0.f, 0.f);
        if (k < kept) v = bx[kept_idx[(size_t)b * NPROP + k]];
        out[(size_t)b * NPROP + k] = v;
    }
}

extern "C" void kernel_launch(void* const* d_in, const int* in_sizes, int n_in,
                              void* d_out, int out_size, void* d_ws, size_t ws_size,
                              hipStream_t stream) {
    const float2* probs = (const float2*)d_in[0];
    const float4* bbox  = (const float4*)d_in[1];
    const float4* anch  = (const float4*)d_in[2];
    char* ws = (char*)d_ws;
    if (ws_size < (size_t)WS_NEED) return;
    uint32_t* hist1 = (uint32_t*)(ws + HIST1_OFF);
    uint32_t* hist2 = (uint32_t*)(ws + HIST2_OFF);
    uint32_t* meta  = (uint32_t*)(ws + META_OFF);
    uint64_t* cand  = (uint64_t*)(ws + CAND_OFF);
    float4*   boxes = (float4*)(ws + BOXES_OFF);
    uint32_t* mask  = (uint32_t*)(ws + MASK_OFF);
    uint32_t* kidx  = (uint32_t*)(ws + KIDX_OFF);

    k_zero<<<dim3((BATCH * (NB1 + NB2) + 255) / 256), dim3(256), 0, stream>>>(hist1);
    k_hist<<<dim3(64), dim3(256), 0, stream>>>(probs, hist1);
    k_thresh<<<dim3(BATCH), dim3(256), 0, stream>>>(hist1, meta);
    k_hist2<<<dim3(64), dim3(256), 0, stream>>>(probs, meta, hist2);
    k_thresh2<<<dim3(BATCH), dim3(256), 0, stream>>>(hist2, meta);
    k_compact<<<dim3(64), dim3(256), 0, stream>>>(probs, meta, meta + 8, cand);
    k_sortdecode<<<dim3(BATCH), dim3(1024), 0, stream>>>(cand, meta, bbox, anch, boxes);
    k_matrix<<<dim3(BATCH * 1024), dim3(256), 0, stream>>>(boxes, mask);
    k_greedy<<<dim3(BATCH), dim3(64), 0, stream>>>(mask, meta, kidx);
    k_finish<<<dim3(BATCH), dim3(1024), 0, stream>>>(boxes, meta, kidx, (float4*)d_out);
}

// Round 2
// 581.690 us; speedup vs baseline: 1.4073x; 1.4073x over previous
//
#include <hip/hip_runtime.h>
#include <stdint.h>

#define BATCH 8
#define NN 262144
#define K_PRE 6000
#define NPROP 1000
#define NMS_THR 0.7f
#define CAND_CAP 8192
#define PREFIX 2048
#define NB1 16384
#define NB2 4096

// workspace layout (bytes)
#define HIST1_OFF 0                                   // BATCH*NB1*4 = 524288
#define HIST2_OFF (HIST1_OFF + BATCH*NB1*4)           // + BATCH*NB2*4 = 131072
#define META_OFF  (HIST2_OFF + BATCH*NB2*4)           // 64 u32 = 256 B
#define CAND_OFF  (META_OFF + 256)
#define BOXES_OFF (CAND_OFF + BATCH*CAND_CAP*8)       // BATCH*K_PRE*16
#define MASK_OFF  (BOXES_OFF + BATCH*K_PRE*16)        // BATCH*PREFIX*64*4 = 4 MB
#define KIDX_OFF  (MASK_OFF + (size_t)BATCH*PREFIX*64*4)
#define WS_NEED   (KIDX_OFF + BATCH*NPROP*4)

__device__ __forceinline__ uint32_t fkey(float f) {
    uint32_t b = __float_as_uint(f);
    return b ^ (uint32_t)(((int32_t)b >> 31) | 0x80000000u);
}

__global__ void k_zero(uint32_t* h) {
    const int i = blockIdx.x * 256 + threadIdx.x;
    if (i < BATCH * (NB1 + NB2)) h[i] = 0;
}

__global__ __launch_bounds__(256) void k_hist(const float2* __restrict__ probs,
                                              uint32_t* __restrict__ hist) {
    __shared__ uint32_t h[NB1];
    for (int i = threadIdx.x; i < NB1; i += 256) h[i] = 0;
    __syncthreads();
    const int b = blockIdx.x >> 3;
    const int s = blockIdx.x & 7;
    const float2* p = probs + (size_t)b * NN + (size_t)s * (NN / 8);
    for (int i = threadIdx.x; i < NN / 8; i += 256) {
        atomicAdd(&h[fkey(p[i].y) >> 18], 1u);
    }
    __syncthreads();
    uint32_t* gh = hist + (size_t)b * NB1;
    for (int i = threadIdx.x; i < NB1; i += 256)
        if (h[i]) atomicAdd(&gh[i], h[i]);
}

__global__ __launch_bounds__(256) void k_thresh(const uint32_t* __restrict__ hist,
                                                uint32_t* meta) {
    const int b = blockIdx.x;
    const uint32_t* gh = hist + (size_t)b * NB1;
    __shared__ uint32_t part[256];
    const int t = threadIdx.x;
    uint32_t s = 0;
    const int hi = NB1 - 64 * t;
    for (int i = hi - 64; i < hi; ++i) s += gh[i];
    part[t] = s;
    __syncthreads();
    if (t == 0) {
        uint32_t cum = 0;
        int strip = 0;
        for (; strip < 256; ++strip) {
            if (cum + part[strip] >= (uint32_t)K_PRE) break;
            cum += part[strip];
        }
        int t1 = 0;
        if (strip < 256) {
            const int top = NB1 - 64 * strip;
            int i = top - 1;
            for (; i >= top - 64; --i) {
                const uint32_t c = gh[i];
                if (cum + c >= (uint32_t)K_PRE) break;
                cum += c;
            }
            if (i < top - 64) i = top - 64;
            t1 = i;
        }
        meta[24 + b] = (uint32_t)t1;
        meta[32 + b] = cum;  // count strictly above bucket t1
    }
}

__global__ __launch_bounds__(256) void k_hist2(const float2* __restrict__ probs,
                                               const uint32_t* __restrict__ meta,
                                               uint32_t* __restrict__ hist2) {
    __shared__ uint32_t h[NB2];
    for (int i = threadIdx.x; i < NB2; i += 256) h[i] = 0;
    __syncthreads();
    const int b = blockIdx.x >> 3;
    const int s = blockIdx.x & 7;
    const uint32_t t1 = meta[24 + b];
    const float2* p = probs + (size_t)b * NN + (size_t)s * (NN / 8);
    for (int i = threadIdx.x; i < NN / 8; i += 256) {
        const uint32_t u = fkey(p[i].y);
        if ((u >> 18) == t1) atomicAdd(&h[(u >> 6) & 0xFFFu], 1u);
    }
    __syncthreads();
    uint32_t* gh = hist2 + (size_t)b * NB2;
    for (int i = threadIdx.x; i < NB2; i += 256)
        if (h[i]) atomicAdd(&gh[i], h[i]);
}

__global__ __launch_bounds__(256) void k_thresh2(const uint32_t* __restrict__ hist2,
                                                 uint32_t* meta) {
    const int b = blockIdx.x;
    const uint32_t* gh = hist2 + (size_t)b * NB2;
    __shared__ uint32_t part[256];
    const int t = threadIdx.x;
    uint32_t s = 0;
    const int hi = NB2 - 16 * t;
    for (int i = hi - 16; i < hi; ++i) s += gh[i];
    part[t] = s;
    __syncthreads();
    if (t == 0) {
        const uint32_t t1 = meta[24 + b];
        uint32_t cum = meta[32 + b];
        int strip = 0;
        for (; strip < 256; ++strip) {
            if (cum + part[strip] >= (uint32_t)K_PRE) break;
            cum += part[strip];
        }
        int sub = 0;
        if (strip < 256) {
            const int top = NB2 - 16 * strip;
            int i = top - 1;
            for (; i >= top - 16; --i) {
                const uint32_t c = gh[i];
                if (cum + c >= (uint32_t)K_PRE) break;
                cum += c;
            }
            if (i < top - 16) i = top - 16;
            sub = i;
        }
        meta[b] = (t1 << 18) | ((uint32_t)sub << 6);
        meta[8 + b] = 0;   // cnt
        meta[16 + b] = 0;  // kept
    }
}

__global__ __launch_bounds__(256) void k_compact(const float2* __restrict__ probs,
                                                 const uint32_t* __restrict__ meta,
                                                 uint32_t* cnt, uint64_t* __restrict__ cand) {
    const int b = blockIdx.x >> 3;
    const int s = blockIdx.x & 7;
    const uint32_t T = meta[b];
    const float2* p = probs + (size_t)b * NN + (size_t)s * (NN / 8);
    const uint32_t base_n = (uint32_t)s * (NN / 8);
    const int lane = threadIdx.x & 63;
    for (int i = threadIdx.x; i < NN / 8; i += 256) {
        const uint32_t u = fkey(p[i].y);
        const bool pass = (u >= T);
        const unsigned long long m = __ballot(pass);
        if (pass) {
            const uint32_t pre = (uint32_t)__popcll(m & ((1ull << lane) - 1ull));
            const int leader = (int)(__ffsll((long long)m) - 1);
            uint32_t base = 0;
            if (lane == leader) base = atomicAdd(&cnt[b], (uint32_t)__popcll(m));
            base = __shfl(base, leader);
            const uint32_t pos = base + pre;
            if (pos < CAND_CAP) {
                const uint32_t n = base_n + (uint32_t)i;
                cand[(size_t)b * CAND_CAP + pos] = ((uint64_t)u << 32) | (uint32_t)(~n);
            }
        }
    }
}

__global__ __launch_bounds__(1024) void k_sortdecode(const uint64_t* __restrict__ cand,
        const uint32_t* __restrict__ meta,
        const float4* __restrict__ bbox, const float4* __restrict__ anch,
        float4* __restrict__ boxes) {
    __shared__ uint64_t key[CAND_CAP];
    const int b = blockIdx.x;
    const uint32_t m = min(meta[8 + b], (uint32_t)CAND_CAP);
    const uint64_t* c = cand + (size_t)b * CAND_CAP;
    for (int i = threadIdx.x; i < CAND_CAP; i += 1024)
        key[i] = (i < (int)m) ? c[i] : 0ull;
    __syncthreads();
    for (int k = 2; k <= CAND_CAP; k <<= 1) {
        for (int j = k >> 1; j > 0; j >>= 1) {
            for (int t = threadIdx.x; t < CAND_CAP / 2; t += 1024) {
                const int i = ((t & ~(j - 1)) << 1) | (t & (j - 1));
                const int p = i | j;
                const uint64_t a = key[i], bb = key[p];
                const bool up = ((i & k) == 0);
                if ((a < bb) == up) { key[i] = bb; key[p] = a; }
            }
            __syncthreads();
        }
    }
    for (int r = threadIdx.x; r < K_PRE; r += 1024) {
        const uint32_t n = ~((uint32_t)key[r]);
        const float4 a = anch[(size_t)b * NN + n];
        const float4 d = bbox[(size_t)b * NN + n];
        float h = a.z - a.x, w = a.w - a.y;
        const float cy0 = a.x + 0.5f * h + d.x * 0.1f * h;
        const float cx0 = a.y + 0.5f * w + d.y * 0.1f * w;
        h = h * expf(d.z * 0.2f);
        w = w * expf(d.w * 0.2f);
        float4 o;
        o.x = fminf(fmaxf(cy0 - 0.5f * h, 0.0f), 1.0f);
        o.y = fminf(fmaxf(cx0 - 0.5f * w, 0.0f), 1.0f);
        o.z = fminf(fmaxf(cy0 + 0.5f * h, 0.0f), 1.0f);
        o.w = fminf(fmaxf(cx0 + 0.5f * w, 0.0f), 1.0f);
        boxes[(size_t)b * K_PRE + r] = o;
    }
}

__global__ __launch_bounds__(256) void k_matrix(const float4* __restrict__ boxes,
                                                uint32_t* __restrict__ mask) {
    const int blk = blockIdx.x;
    const int b = blk >> 10;
    const int tile = blk & 1023;
    const int ti = tile >> 5, tj = tile & 31;
    __shared__ float4 rb[64], cb[64];
    __shared__ uint32_t wbits[128];
    const float4* bx = boxes + (size_t)b * K_PRE;
    const int t = threadIdx.x;
    if (t < 64) rb[t] = bx[ti * 64 + t];
    else if (t < 128) cb[t - 64] = bx[tj * 64 + (t - 64)];
    if (t < 128) wbits[t] = 0;
    __syncthreads();
    const int r = t >> 2;
    const int cq = t & 3;
    const float4 a = rb[r];
    const float areaA = (a.z - a.x) * (a.w - a.y);
    uint32_t bits = 0;
#pragma unroll
    for (int jj = 0; jj < 16; ++jj) {
        const float4 cc = cb[cq * 16 + jj];
        const float yy1 = fmaxf(a.x, cc.x), xx1 = fmaxf(a.y, cc.y);
        const float yy2 = fminf(a.z, cc.z), xx2 = fminf(a.w, cc.w);
        const float inter = fmaxf(yy2 - yy1, 0.0f) * fmaxf(xx2 - xx1, 0.0f);
        const float areaC = (cc.z - cc.x) * (cc.w - cc.y);
        const float uni = fmaxf(areaA + areaC - inter, 1e-8f);
        if (inter / uni > NMS_THR) bits |= (1u << jj);
    }
    atomicOr(&wbits[r * 2 + (cq >> 1)], bits << ((cq & 1) * 16));
    __syncthreads();
    if (t < 128) {
        const int rr = t >> 1, ww = t & 1;
        mask[((size_t)b * PREFIX + ti * 64 + rr) * 64 + tj * 2 + ww] = wbits[rr * 2 + ww];
    }
}

// Greedy NMS bit-scan over the 2048x2048 suppression matrix.
// 256 threads: wave 0 runs the serial scan from LDS; waves 1-3 stage the
// next 256-row (64KB) chunk from global into the other LDS buffer.
__global__ __launch_bounds__(256) void k_greedy(const uint32_t* __restrict__ mask,
                                                uint32_t* meta, uint32_t* __restrict__ kept_idx) {
    __shared__ uint32_t lbuf[2][256 * 64];   // 2 x 64 KB
    __shared__ uint32_t skept[8];
    const int b = blockIdx.x;
    const int lane = threadIdx.x & 63;
    const int wave = threadIdx.x >> 6;
    const uint32_t* mrow = mask + (size_t)b * PREFIX * 64;

    // stage chunk 0 with all 4 waves
    {
        const uint4* s4 = (const uint4*)mrow;
        uint4* d4 = (uint4*)lbuf[0];
        for (int idx = threadIdx.x; idx < 4096; idx += 256) d4[idx] = s4[idx];
    }
    __syncthreads();

    uint32_t supp = 0;   // lane l: suppression bits for columns [32l, 32l+32)
    uint32_t kept = 0;

    for (int c = 0; c < PREFIX / 256; ++c) {
        if (wave > 0) {
            if (c + 1 < PREFIX / 256) {
                const uint4* s4 = (const uint4*)(mrow + (size_t)(c + 1) * 256 * 64);
                uint4* d4 = (uint4*)lbuf[(c + 1) & 1];
                for (int idx = threadIdx.x - 64; idx < 4096; idx += 192) d4[idx] = s4[idx];
            }
        } else {
            const uint32_t* L = lbuf[c & 1];
            for (int g = 0; g < 8; ++g) {
                if (kept >= NPROP) break;
                const int grow = c * 256 + g * 32;
                const int w = grow >> 5;
                uint32_t rbuf[32];
#pragma unroll
                for (int q = 0; q < 32; ++q) rbuf[q] = L[(g * 32 + q) * 64 + lane];
                uint32_t sw = __builtin_amdgcn_readlane(supp, w);
#pragma unroll
                for (int q = 0; q < 32; ++q) {
                    if (kept < NPROP && !((sw >> q) & 1u)) {
                        if (lane == 0) kept_idx[(size_t)b * NPROP + kept] = (uint32_t)(grow + q);
                        supp |= rbuf[q];
                        sw |= __builtin_amdgcn_readlane(rbuf[q], w);
                        ++kept;
                    }
                }
            }
            if (lane == 0) skept[c] = kept;
        }
        __syncthreads();
        if (skept[c] >= NPROP) break;
    }
    if (wave == 0 && lane == 0) meta[16 + b] = kept;
}

__global__ __launch_bounds__(1024) void k_finish(const float4* __restrict__ boxes,
        uint32_t* meta, uint32_t* kept_idx, float4* __restrict__ out) {
    const int b = blockIdx.x;
    const float4* bx = boxes + (size_t)b * K_PRE;
    __shared__ float4 kb[NPROP];
    __shared__ uint32_t sflag;
    uint32_t kept = meta[16 + b];
    if (kept < NPROP) {
        for (uint32_t k = threadIdx.x; k < kept; k += 1024)
            kb[k] = bx[kept_idx[(size_t)b * NPROP + k]];
        __syncthreads();
        for (int i = PREFIX; i < K_PRE && kept < NPROP; ++i) {
            if (threadIdx.x == 0) sflag = 0;
            __syncthreads();
            const float4 c = bx[i];
            const float areaC = (c.z - c.x) * (c.w - c.y);
            bool sup = false;
            for (uint32_t k = threadIdx.x; k < kept; k += 1024) {
                const float4 a = kb[k];
                const float yy1 = fmaxf(c.x, a.x), xx1 = fmaxf(c.y, a.y);
                const float yy2 = fminf(c.z, a.z), xx2 = fminf(c.w, a.w);
                const float inter = fmaxf(yy2 - yy1, 0.0f) * fmaxf(xx2 - xx1, 0.0f);
                const float areaA = (a.z - a.x) * (a.w - a.y);
                const float uni = fmaxf(areaC + areaA - inter, 1e-8f);
                if (inter / uni > NMS_THR) { sup = true; break; }
            }
            if (sup) atomicOr(&sflag, 1u);
            __syncthreads();
            if (sflag == 0) {
                if (threadIdx.x == 0) {
                    kept_idx[(size_t)b * NPROP + kept] = (uint32_t)i;
                    kb[kept] = c;
                }
                ++kept;
            }
            __syncthreads();
        }
        if (threadIdx.x == 0) meta[16 + b] = kept;
    }
    __syncthreads();
    for (uint32_t k = threadIdx.x; k < NPROP; k += 1024) {
        float4 v = make_float4(0.f, 0.f, 0.f, 0.f);
        if (k < kept) v = bx[kept_idx[(size_t)b * NPROP + k]];
        out[(size_t)b * NPROP + k] = v;
    }
}

extern "C" void kernel_launch(void* const* d_in, const int* in_sizes, int n_in,
                              void* d_out, int out_size, void* d_ws, size_t ws_size,
                              hipStream_t stream) {
    const float2* probs = (const float2*)d_in[0];
    const float4* bbox  = (const float4*)d_in[1];
    const float4* anch  = (const float4*)d_in[2];
    char* ws = (char*)d_ws;
    if (ws_size < (size_t)WS_NEED) return;
    uint32_t* hist1 = (uint32_t*)(ws + HIST1_OFF);
    uint32_t* hist2 = (uint32_t*)(ws + HIST2_OFF);
    uint32_t* meta  = (uint32_t*)(ws + META_OFF);
    uint64_t* cand  = (uint64_t*)(ws + CAND_OFF);
    float4*   boxes = (float4*)(ws + BOXES_OFF);
    uint32_t* mask  = (uint32_t*)(ws + MASK_OFF);
    uint32_t* kidx  = (uint32_t*)(ws + KIDX_OFF);

    k_zero<<<dim3((BATCH * (NB1 + NB2) + 255) / 256), dim3(256), 0, stream>>>(hist1);
    k_hist<<<dim3(64), dim3(256), 0, stream>>>(probs, hist1);
    k_thresh<<<dim3(BATCH), dim3(256), 0, stream>>>(hist1, meta);
    k_hist2<<<dim3(64), dim3(256), 0, stream>>>(probs, meta, hist2);
    k_thresh2<<<dim3(BATCH), dim3(256), 0, stream>>>(hist2, meta);
    k_compact<<<dim3(64), dim3(256), 0, stream>>>(probs, meta, meta + 8, cand);
    k_sortdecode<<<dim3(BATCH), dim3(1024), 0, stream>>>(cand, meta, bbox, anch, boxes);
    k_matrix<<<dim3(BATCH * 1024), dim3(256), 0, stream>>>(boxes, mask);
    k_greedy<<<dim3(BATCH), dim3(256), 0, stream>>>(mask, meta, kidx);
    k_finish<<<dim3(BATCH), dim3(1024), 0, stream>>>(boxes, meta, kidx, (float4*)d_out);
}

// Round 3
// 532.322 us; speedup vs baseline: 1.5378x; 1.0927x over previous
//
#include <hip/hip_runtime.h>
#include <stdint.h>

#define BATCH 8
#define NN 262144
#define K_PRE 6000
#define NPROP 1000
#define NMS_THR 0.7f
#define CAND_CAP 8192
#define PREFIX 2048
#define NB1 16384
#define NB2 4096

// workspace layout (bytes)
#define HIST1_OFF 0                                   // BATCH*NB1*4 = 524288
#define HIST2_OFF (HIST1_OFF + BATCH*NB1*4)           // + BATCH*NB2*4 = 131072
#define META_OFF  (HIST2_OFF + BATCH*NB2*4)           // 64 u32 = 256 B
#define CAND_OFF  (META_OFF + 256)
#define BOXES_OFF (CAND_OFF + BATCH*CAND_CAP*8)       // BATCH*K_PRE*16
#define MASK_OFF  (BOXES_OFF + BATCH*K_PRE*16)        // BATCH*PREFIX*64*4 = 4 MB
#define KIDX_OFF  (MASK_OFF + (size_t)BATCH*PREFIX*64*4)
#define WS_NEED   (KIDX_OFF + BATCH*NPROP*4)

__device__ __forceinline__ uint32_t fkey(float f) {
    uint32_t b = __float_as_uint(f);
    return b ^ (uint32_t)(((int32_t)b >> 31) | 0x80000000u);
}

__global__ void k_zero(uint32_t* h) {
    const int i = blockIdx.x * 256 + threadIdx.x;
    if (i < BATCH * (NB1 + NB2)) h[i] = 0;
}

// 512 blocks = 64 per batch; each block: 2048 float4 (= 4096 elements).
// LDS histogram aggregates before global atomics (hot >>18 buckets hold
// ~4k elements each for uniform scores -> direct global atomics would
// serialize badly).
__global__ __launch_bounds__(256) void k_hist(const float4* __restrict__ probs4,
                                              uint32_t* __restrict__ hist) {
    __shared__ uint32_t h[NB1];
    for (int i = threadIdx.x; i < NB1; i += 256) h[i] = 0;
    __syncthreads();
    const int b = blockIdx.x >> 6;
    const int s = blockIdx.x & 63;
    const float4* p = probs4 + (size_t)b * (NN / 2) + (size_t)s * 2048;
    for (int i = threadIdx.x; i < 2048; i += 256) {
        const float4 v = p[i];
        atomicAdd(&h[fkey(v.y) >> 18], 1u);
        atomicAdd(&h[fkey(v.w) >> 18], 1u);
    }
    __syncthreads();
    uint32_t* gh = hist + (size_t)b * NB1;
    for (int i = threadIdx.x; i < NB1; i += 256)
        if (h[i]) atomicAdd(&gh[i], h[i]);
}

__global__ __launch_bounds__(256) void k_thresh(const uint32_t* __restrict__ hist,
                                                uint32_t* meta) {
    const int b = blockIdx.x;
    const uint32_t* gh = hist + (size_t)b * NB1;
    __shared__ uint32_t part[256];
    const int t = threadIdx.x;
    uint32_t s = 0;
    const int hi = NB1 - 64 * t;
    for (int i = hi - 64; i < hi; ++i) s += gh[i];
    part[t] = s;
    __syncthreads();
    if (t == 0) {
        uint32_t cum = 0;
        int strip = 0;
        for (; strip < 256; ++strip) {
            if (cum + part[strip] >= (uint32_t)K_PRE) break;
            cum += part[strip];
        }
        int t1 = 0;
        if (strip < 256) {
            const int top = NB1 - 64 * strip;
            int i = top - 1;
            for (; i >= top - 64; --i) {
                const uint32_t c = gh[i];
                if (cum + c >= (uint32_t)K_PRE) break;
                cum += c;
            }
            if (i < top - 64) i = top - 64;
            t1 = i;
        }
        meta[24 + b] = (uint32_t)t1;
        meta[32 + b] = cum;  // count strictly above bucket t1
    }
}

// 2048 blocks = 256 per batch; each block 512 float4. Only ~8k elements per
// batch land in bucket t1 -> direct global atomics are uncontended.
__global__ __launch_bounds__(256) void k_hist2(const float4* __restrict__ probs4,
                                               const uint32_t* __restrict__ meta,
                                               uint32_t* __restrict__ hist2) {
    const int b = blockIdx.x >> 8;
    const int s = blockIdx.x & 255;
    const uint32_t t1 = meta[24 + b];
    const float4* p = probs4 + (size_t)b * (NN / 2) + (size_t)s * 512;
    uint32_t* gh = hist2 + (size_t)b * NB2;
    for (int i = threadIdx.x; i < 512; i += 256) {
        const float4 v = p[i];
        const uint32_t u1 = fkey(v.y);
        const uint32_t u2 = fkey(v.w);
        if ((u1 >> 18) == t1) atomicAdd(&gh[(u1 >> 6) & 0xFFFu], 1u);
        if ((u2 >> 18) == t1) atomicAdd(&gh[(u2 >> 6) & 0xFFFu], 1u);
    }
}

__global__ __launch_bounds__(256) void k_thresh2(const uint32_t* __restrict__ hist2,
                                                 uint32_t* meta) {
    const int b = blockIdx.x;
    const uint32_t* gh = hist2 + (size_t)b * NB2;
    __shared__ uint32_t part[256];
    const int t = threadIdx.x;
    uint32_t s = 0;
    const int hi = NB2 - 16 * t;
    for (int i = hi - 16; i < hi; ++i) s += gh[i];
    part[t] = s;
    __syncthreads();
    if (t == 0) {
        const uint32_t t1 = meta[24 + b];
        uint32_t cum = meta[32 + b];
        int strip = 0;
        for (; strip < 256; ++strip) {
            if (cum + part[strip] >= (uint32_t)K_PRE) break;
            cum += part[strip];
        }
        int sub = 0;
        if (strip < 256) {
            const int top = NB2 - 16 * strip;
            int i = top - 1;
            for (; i >= top - 16; --i) {
                const uint32_t c = gh[i];
                if (cum + c >= (uint32_t)K_PRE) break;
                cum += c;
            }
            if (i < top - 16) i = top - 16;
            sub = i;
        }
        meta[b] = (t1 << 18) | ((uint32_t)sub << 6);
        meta[8 + b] = 0;   // cnt
        meta[16 + b] = 0;  // kept
    }
}

// 2048 blocks = 256 per batch. Order within cand[] is irrelevant (the 64-bit
// key carries the full sort order), so wave-aggregated atomic append is fine.
__global__ __launch_bounds__(256) void k_compact(const float4* __restrict__ probs4,
                                                 const uint32_t* __restrict__ meta,
                                                 uint32_t* cnt, uint64_t* __restrict__ cand) {
    const int b = blockIdx.x >> 8;
    const int s = blockIdx.x & 255;
    const uint32_t T = meta[b];
    const float4* p = probs4 + (size_t)b * (NN / 2) + (size_t)s * 512;
    const uint32_t base_n = (uint32_t)s * 1024;
    const int lane = threadIdx.x & 63;
    uint64_t* cb = cand + (size_t)b * CAND_CAP;
    for (int i = threadIdx.x; i < 512; i += 256) {
        const float4 v = p[i];
        const uint32_t u1 = fkey(v.y);
        const uint32_t u2 = fkey(v.w);
        {
            const bool pass = (u1 >= T);
            const unsigned long long m = __ballot(pass);
            if (pass) {
                const uint32_t pre = (uint32_t)__popcll(m & ((1ull << lane) - 1ull));
                const int leader = (int)(__ffsll((long long)m) - 1);
                uint32_t base = 0;
                if (lane == leader) base = atomicAdd(&cnt[b], (uint32_t)__popcll(m));
                base = __shfl(base, leader);
                const uint32_t pos = base + pre;
                if (pos < CAND_CAP) {
                    const uint32_t n = base_n + 2u * (uint32_t)i;
                    cb[pos] = ((uint64_t)u1 << 32) | (uint32_t)(~n);
                }
            }
        }
        {
            const bool pass = (u2 >= T);
            const unsigned long long m = __ballot(pass);
            if (pass) {
                const uint32_t pre = (uint32_t)__popcll(m & ((1ull << lane) - 1ull));
                const int leader = (int)(__ffsll((long long)m) - 1);
                uint32_t base = 0;
                if (lane == leader) base = atomicAdd(&cnt[b], (uint32_t)__popcll(m));
                base = __shfl(base, leader);
                const uint32_t pos = base + pre;
                if (pos < CAND_CAP) {
                    const uint32_t n = base_n + 2u * (uint32_t)i + 1u;
                    cb[pos] = ((uint64_t)u2 << 32) | (uint32_t)(~n);
                }
            }
        }
    }
}

__global__ __launch_bounds__(1024) void k_sortdecode(const uint64_t* __restrict__ cand,
        const uint32_t* __restrict__ meta,
        const float4* __restrict__ bbox, const float4* __restrict__ anch,
        float4* __restrict__ boxes) {
    __shared__ uint64_t key[CAND_CAP];
    const int b = blockIdx.x;
    const uint32_t m = min(meta[8 + b], (uint32_t)CAND_CAP);
    const uint64_t* c = cand + (size_t)b * CAND_CAP;
    for (int i = threadIdx.x; i < CAND_CAP; i += 1024)
        key[i] = (i < (int)m) ? c[i] : 0ull;
    __syncthreads();
    for (int k = 2; k <= CAND_CAP; k <<= 1) {
        for (int j = k >> 1; j > 0; j >>= 1) {
            for (int t = threadIdx.x; t < CAND_CAP / 2; t += 1024) {
                const int i = ((t & ~(j - 1)) << 1) | (t & (j - 1));
                const int p = i | j;
                const uint64_t a = key[i], bb = key[p];
                const bool up = ((i & k) == 0);
                if ((a < bb) == up) { key[i] = bb; key[p] = a; }
            }
            __syncthreads();
        }
    }
    for (int r = threadIdx.x; r < K_PRE; r += 1024) {
        const uint32_t n = ~((uint32_t)key[r]);
        const float4 a = anch[(size_t)b * NN + n];
        const float4 d = bbox[(size_t)b * NN + n];
        float h = a.z - a.x, w = a.w - a.y;
        const float cy0 = a.x + 0.5f * h + d.x * 0.1f * h;
        const float cx0 = a.y + 0.5f * w + d.y * 0.1f * w;
        h = h * expf(d.z * 0.2f);
        w = w * expf(d.w * 0.2f);
        float4 o;
        o.x = fminf(fmaxf(cy0 - 0.5f * h, 0.0f), 1.0f);
        o.y = fminf(fmaxf(cx0 - 0.5f * w, 0.0f), 1.0f);
        o.z = fminf(fmaxf(cy0 + 0.5f * h, 0.0f), 1.0f);
        o.w = fminf(fmaxf(cx0 + 0.5f * w, 0.0f), 1.0f);
        boxes[(size_t)b * K_PRE + r] = o;
    }
}

__global__ __launch_bounds__(256) void k_matrix(const float4* __restrict__ boxes,
                                                uint32_t* __restrict__ mask) {
    const int blk = blockIdx.x;
    const int b = blk >> 10;
    const int tile = blk & 1023;
    const int ti = tile >> 5, tj = tile & 31;
    __shared__ float4 rb[64], cb[64];
    __shared__ uint32_t wbits[128];
    const float4* bx = boxes + (size_t)b * K_PRE;
    const int t = threadIdx.x;
    if (t < 64) rb[t] = bx[ti * 64 + t];
    else if (t < 128) cb[t - 64] = bx[tj * 64 + (t - 64)];
    if (t < 128) wbits[t] = 0;
    __syncthreads();
    const int r = t >> 2;
    const int cq = t & 3;
    const float4 a = rb[r];
    const float areaA = (a.z - a.x) * (a.w - a.y);
    uint32_t bits = 0;
#pragma unroll
    for (int jj = 0; jj < 16; ++jj) {
        const float4 cc = cb[cq * 16 + jj];
        const float yy1 = fmaxf(a.x, cc.x), xx1 = fmaxf(a.y, cc.y);
        const float yy2 = fminf(a.z, cc.z), xx2 = fminf(a.w, cc.w);
        const float inter = fmaxf(yy2 - yy1, 0.0f) * fmaxf(xx2 - xx1, 0.0f);
        const float areaC = (cc.z - cc.x) * (cc.w - cc.y);
        const float uni = fmaxf(areaA + areaC - inter, 1e-8f);
        if (inter / uni > NMS_THR) bits |= (1u << jj);
    }
    atomicOr(&wbits[r * 2 + (cq >> 1)], bits << ((cq & 1) * 16));
    __syncthreads();
    if (t < 128) {
        const int rr = t >> 1, ww = t & 1;
        mask[((size_t)b * PREFIX + ti * 64 + rr) * 64 + tj * 2 + ww] = wbits[rr * 2 + ww];
    }
}

// Greedy NMS bit-scan over the 2048x2048 suppression matrix.
// 256 threads: wave 0 runs the serial scan from LDS; waves 1-3 stage the
// next 256-row (64KB) chunk from global into the other LDS buffer.
__global__ __launch_bounds__(256) void k_greedy(const uint32_t* __restrict__ mask,
                                                uint32_t* meta, uint32_t* __restrict__ kept_idx) {
    __shared__ uint32_t lbuf[2][256 * 64];   // 2 x 64 KB
    __shared__ uint32_t skept[8];
    const int b = blockIdx.x;
    const int lane = threadIdx.x & 63;
    const int wave = threadIdx.x >> 6;
    const uint32_t* mrow = mask + (size_t)b * PREFIX * 64;

    // stage chunk 0 with all 4 waves
    {
        const uint4* s4 = (const uint4*)mrow;
        uint4* d4 = (uint4*)lbuf[0];
        for (int idx = threadIdx.x; idx < 4096; idx += 256) d4[idx] = s4[idx];
    }
    __syncthreads();

    uint32_t supp = 0;   // lane l: suppression bits for columns [32l, 32l+32)
    uint32_t kept = 0;

    for (int c = 0; c < PREFIX / 256; ++c) {
        if (wave > 0) {
            if (c + 1 < PREFIX / 256) {
                const uint4* s4 = (const uint4*)(mrow + (size_t)(c + 1) * 256 * 64);
                uint4* d4 = (uint4*)lbuf[(c + 1) & 1];
                for (int idx = threadIdx.x - 64; idx < 4096; idx += 192) d4[idx] = s4[idx];
            }
        } else {
            const uint32_t* L = lbuf[c & 1];
            for (int g = 0; g < 8; ++g) {
                if (kept >= NPROP) break;
                const int grow = c * 256 + g * 32;
                const int w = grow >> 5;
                uint32_t rbuf[32];
#pragma unroll
                for (int q = 0; q < 32; ++q) rbuf[q] = L[(g * 32 + q) * 64 + lane];
                uint32_t sw = __builtin_amdgcn_readlane(supp, w);
#pragma unroll
                for (int q = 0; q < 32; ++q) {
                    if (kept < NPROP && !((sw >> q) & 1u)) {
                        if (lane == 0) kept_idx[(size_t)b * NPROP + kept] = (uint32_t)(grow + q);
                        supp |= rbuf[q];
                        sw |= __builtin_amdgcn_readlane(rbuf[q], w);
                        ++kept;
                    }
                }
            }
            if (lane == 0) skept[c] = kept;
        }
        __syncthreads();
        if (skept[c] >= NPROP) break;
    }
    if (wave == 0 && lane == 0) meta[16 + b] = kept;
}

__global__ __launch_bounds__(1024) void k_finish(const float4* __restrict__ boxes,
        uint32_t* meta, uint32_t* kept_idx, float4* __restrict__ out) {
    const int b = blockIdx.x;
    const float4* bx = boxes + (size_t)b * K_PRE;
    __shared__ float4 kb[NPROP];
    __shared__ uint32_t sflag;
    uint32_t kept = meta[16 + b];
    if (kept < NPROP) {
        for (uint32_t k = threadIdx.x; k < kept; k += 1024)
            kb[k] = bx[kept_idx[(size_t)b * NPROP + k]];
        __syncthreads();
        for (int i = PREFIX; i < K_PRE && kept < NPROP; ++i) {
            if (threadIdx.x == 0) sflag = 0;
            __syncthreads();
            const float4 c = bx[i];
            const float areaC = (c.z - c.x) * (c.w - c.y);
            bool sup = false;
            for (uint32_t k = threadIdx.x; k < kept; k += 1024) {
                const float4 a = kb[k];
                const float yy1 = fmaxf(c.x, a.x), xx1 = fmaxf(c.y, a.y);
                const float yy2 = fminf(c.z, a.z), xx2 = fminf(c.w, a.w);
                const float inter = fmaxf(yy2 - yy1, 0.0f) * fmaxf(xx2 - xx1, 0.0f);
                const float areaA = (a.z - a.x) * (a.w - a.y);
                const float uni = fmaxf(areaC + areaA - inter, 1e-8f);
                if (inter / uni > NMS_THR) { sup = true; break; }
            }
            if (sup) atomicOr(&sflag, 1u);
            __syncthreads();
            if (sflag == 0) {
                if (threadIdx.x == 0) {
                    kept_idx[(size_t)b * NPROP + kept] = (uint32_t)i;
                    kb[kept] = c;
                }
                ++kept;
            }
            __syncthreads();
        }
        if (threadIdx.x == 0) meta[16 + b] = kept;
    }
    __syncthreads();
    for (uint32_t k = threadIdx.x; k < NPROP; k += 1024) {
        float4 v = make_float4(0.f, 0.f, 0.f, 0.f);
        if (k < kept) v = bx[kept_idx[(size_t)b * NPROP + k]];
        out[(size_t)b * NPROP + k] = v;
    }
}

extern "C" void kernel_launch(void* const* d_in, const int* in_sizes, int n_in,
                              void* d_out, int out_size, void* d_ws, size_t ws_size,
                              hipStream_t stream) {
    const float4* probs4 = (const float4*)d_in[0];
    const float4* bbox   = (const float4*)d_in[1];
    const float4* anch   = (const float4*)d_in[2];
    char* ws = (char*)d_ws;
    if (ws_size < (size_t)WS_NEED) return;
    uint32_t* hist1 = (uint32_t*)(ws + HIST1_OFF);
    uint32_t* hist2 = (uint32_t*)(ws + HIST2_OFF);
    uint32_t* meta  = (uint32_t*)(ws + META_OFF);
    uint64_t* cand  = (uint64_t*)(ws + CAND_OFF);
    float4*   boxes = (float4*)(ws + BOXES_OFF);
    uint32_t* mask  = (uint32_t*)(ws + MASK_OFF);
    uint32_t* kidx  = (uint32_t*)(ws + KIDX_OFF);

    k_zero<<<dim3((BATCH * (NB1 + NB2) + 255) / 256), dim3(256), 0, stream>>>(hist1);
    k_hist<<<dim3(512), dim3(256), 0, stream>>>(probs4, hist1);
    k_thresh<<<dim3(BATCH), dim3(256), 0, stream>>>(hist1, meta);
    k_hist2<<<dim3(2048), dim3(256), 0, stream>>>(probs4, meta, hist2);
    k_thresh2<<<dim3(BATCH), dim3(256), 0, stream>>>(hist2, meta);
    k_compact<<<dim3(2048), dim3(256), 0, stream>>>(probs4, meta, meta + 8, cand);
    k_sortdecode<<<dim3(BATCH), dim3(1024), 0, stream>>>(cand, meta, bbox, anch, boxes);
    k_matrix<<<dim3(BATCH * 1024), dim3(256), 0, stream>>>(boxes, mask);
    k_greedy<<<dim3(BATCH), dim3(256), 0, stream>>>(mask, meta, kidx);
    k_finish<<<dim3(BATCH), dim3(1024), 0, stream>>>(boxes, meta, kidx, (float4*)d_out);
}

// Round 4
// 248.028 us; speedup vs baseline: 3.3004x; 2.1462x over previous
//
#include <hip/hip_runtime.h>
#include <stdint.h>

#define BATCH 8
#define NN 262144
#define K_PRE 6000
#define NPROP 1000
#define NMS_THR 0.7f
#define CAND_CAP 8192
#define PREFIX 2048
#define NB1 16384
#define NB2 4096

// meta u32 indices
#define MT_T2 0        // [0..7]   final threshold (read-only after thresh2)
#define MT_KEPT 16     // [16..23] kept count per batch
#define MT_T1 24       // [24..31] coarse bucket
#define MT_CUM 32      // [32..39] cum count above coarse bucket
#define MT_CNT(b) (64 + 32*(b))   // padded counters, 128B apart

// workspace layout (bytes)
#define HIST1_OFF 0                                   // BATCH*NB1*4 = 524288
#define HIST2_OFF (HIST1_OFF + BATCH*NB1*4)           // + BATCH*NB2*4 = 131072
#define META_OFF  (HIST2_OFF + BATCH*NB2*4)           // 2048 B
#define CAND_OFF  (META_OFF + 2048)
#define BOXES_OFF (CAND_OFF + BATCH*CAND_CAP*8)       // BATCH*K_PRE*16
#define MASK_OFF  (BOXES_OFF + BATCH*K_PRE*16)        // BATCH*PREFIX*64*4 = 4 MB
#define KIDX_OFF  (MASK_OFF + (size_t)BATCH*PREFIX*64*4)
#define WS_NEED   (KIDX_OFF + BATCH*NPROP*4)

__device__ __forceinline__ uint32_t fkey(float f) {
    uint32_t b = __float_as_uint(f);
    return b ^ (uint32_t)(((int32_t)b >> 31) | 0x80000000u);
}

__global__ void k_zero(uint32_t* h) {
    const int i = blockIdx.x * 256 + threadIdx.x;
    if (i < BATCH * (NB1 + NB2)) h[i] = 0;
}

// 512 blocks = 64 per batch; each block: 2048 float4 (= 4096 elements).
__global__ __launch_bounds__(256) void k_hist(const float4* __restrict__ probs4,
                                              uint32_t* __restrict__ hist) {
    __shared__ uint32_t h[NB1];
    for (int i = threadIdx.x; i < NB1; i += 256) h[i] = 0;
    __syncthreads();
    const int b = blockIdx.x >> 6;
    const int s = blockIdx.x & 63;
    const float4* p = probs4 + (size_t)b * (NN / 2) + (size_t)s * 2048;
    for (int i = threadIdx.x; i < 2048; i += 256) {
        const float4 v = p[i];
        atomicAdd(&h[fkey(v.y) >> 18], 1u);
        atomicAdd(&h[fkey(v.w) >> 18], 1u);
    }
    __syncthreads();
    uint32_t* gh = hist + (size_t)b * NB1;
    for (int i = threadIdx.x; i < NB1; i += 256)
        if (h[i]) atomicAdd(&gh[i], h[i]);
}

__global__ __launch_bounds__(256) void k_thresh(const uint32_t* __restrict__ hist,
                                                uint32_t* meta) {
    const int b = blockIdx.x;
    const uint32_t* gh = hist + (size_t)b * NB1;
    __shared__ uint32_t part[256];
    const int t = threadIdx.x;
    uint32_t s = 0;
    const int hi = NB1 - 64 * t;
    for (int i = hi - 64; i < hi; ++i) s += gh[i];
    part[t] = s;
    __syncthreads();
    if (t == 0) {
        uint32_t cum = 0;
        int strip = 0;
        for (; strip < 256; ++strip) {
            if (cum + part[strip] >= (uint32_t)K_PRE) break;
            cum += part[strip];
        }
        int t1 = 0;
        if (strip < 256) {
            const int top = NB1 - 64 * strip;
            int i = top - 1;
            for (; i >= top - 64; --i) {
                const uint32_t c = gh[i];
                if (cum + c >= (uint32_t)K_PRE) break;
                cum += c;
            }
            if (i < top - 64) i = top - 64;
            t1 = i;
        }
        meta[MT_T1 + b] = (uint32_t)t1;
        meta[MT_CUM + b] = cum;  // count strictly above bucket t1
    }
}

// 2048 blocks = 256 per batch; ~8k matches per batch spread over 4096 buckets.
__global__ __launch_bounds__(256) void k_hist2(const float4* __restrict__ probs4,
                                               const uint32_t* __restrict__ meta,
                                               uint32_t* __restrict__ hist2) {
    const int b = blockIdx.x >> 8;
    const int s = blockIdx.x & 255;
    const uint32_t t1 = meta[MT_T1 + b];
    const float4* p = probs4 + (size_t)b * (NN / 2) + (size_t)s * 512;
    uint32_t* gh = hist2 + (size_t)b * NB2;
    for (int i = threadIdx.x; i < 512; i += 256) {
        const float4 v = p[i];
        const uint32_t u1 = fkey(v.y);
        const uint32_t u2 = fkey(v.w);
        if ((u1 >> 18) == t1) atomicAdd(&gh[(u1 >> 6) & 0xFFFu], 1u);
        if ((u2 >> 18) == t1) atomicAdd(&gh[(u2 >> 6) & 0xFFFu], 1u);
    }
}

__global__ __launch_bounds__(256) void k_thresh2(const uint32_t* __restrict__ hist2,
                                                 uint32_t* meta) {
    const int b = blockIdx.x;
    const uint32_t* gh = hist2 + (size_t)b * NB2;
    __shared__ uint32_t part[256];
    const int t = threadIdx.x;
    uint32_t s = 0;
    const int hi = NB2 - 16 * t;
    for (int i = hi - 16; i < hi; ++i) s += gh[i];
    part[t] = s;
    __syncthreads();
    if (t == 0) {
        const uint32_t t1 = meta[MT_T1 + b];
        uint32_t cum = meta[MT_CUM + b];
        int strip = 0;
        for (; strip < 256; ++strip) {
            if (cum + part[strip] >= (uint32_t)K_PRE) break;
            cum += part[strip];
        }
        int sub = 0;
        if (strip < 256) {
            const int top = NB2 - 16 * strip;
            int i = top - 1;
            for (; i >= top - 16; --i) {
                const uint32_t c = gh[i];
                if (cum + c >= (uint32_t)K_PRE) break;
                cum += c;
            }
            if (i < top - 16) i = top - 16;
            sub = i;
        }
        meta[MT_T2 + b] = (t1 << 18) | ((uint32_t)sub << 6);
        meta[MT_CNT(b)] = 0;
        meta[MT_KEPT + b] = 0;
    }
}

// 2048 blocks = 256 per batch. Contention-free: LDS stash + ONE padded global
// atomic per block. cand[] slot order is irrelevant (key carries full order).
__global__ __launch_bounds__(256) void k_compact(const float4* __restrict__ probs4,
                                                 const uint32_t* __restrict__ meta,
                                                 uint32_t* cnt_meta, uint64_t* __restrict__ cand) {
    __shared__ uint64_t stash[1024];
    __shared__ uint32_t lcnt, lbase;
    const int b = blockIdx.x >> 8;
    const int s = blockIdx.x & 255;
    const uint32_t T = meta[MT_T2 + b];
    if (threadIdx.x == 0) lcnt = 0;
    __syncthreads();
    const float4* p = probs4 + (size_t)b * (NN / 2) + (size_t)s * 512;
    const uint32_t base_n = (uint32_t)s * 1024;
    for (int i = threadIdx.x; i < 512; i += 256) {
        const float4 v = p[i];
        const uint32_t u1 = fkey(v.y);
        const uint32_t u2 = fkey(v.w);
        if (u1 >= T) {
            const uint32_t pos = atomicAdd(&lcnt, 1u);
            const uint32_t n = base_n + 2u * (uint32_t)i;
            stash[pos] = ((uint64_t)u1 << 32) | (uint32_t)(~n);
        }
        if (u2 >= T) {
            const uint32_t pos = atomicAdd(&lcnt, 1u);
            const uint32_t n = base_n + 2u * (uint32_t)i + 1u;
            stash[pos] = ((uint64_t)u2 << 32) | (uint32_t)(~n);
        }
    }
    __syncthreads();
    if (threadIdx.x == 0) lbase = atomicAdd(&cnt_meta[MT_CNT(b)], lcnt);
    __syncthreads();
    uint64_t* cb = cand + (size_t)b * CAND_CAP;
    const uint32_t n_loc = lcnt, base = lbase;
    for (uint32_t i = threadIdx.x; i < n_loc; i += 256) {
        const uint32_t pos = base + i;
        if (pos < CAND_CAP) cb[pos] = stash[i];
    }
}

__global__ __launch_bounds__(1024) void k_sortdecode(const uint64_t* __restrict__ cand,
        const uint32_t* __restrict__ meta,
        const float4* __restrict__ bbox, const float4* __restrict__ anch,
        float4* __restrict__ boxes) {
    __shared__ uint64_t key[CAND_CAP];
    const int b = blockIdx.x;
    const uint32_t m = min(meta[MT_CNT(b)], (uint32_t)CAND_CAP);
    const uint64_t* c = cand + (size_t)b * CAND_CAP;
    for (int i = threadIdx.x; i < CAND_CAP; i += 1024)
        key[i] = (i < (int)m) ? c[i] : 0ull;
    __syncthreads();
    for (int k = 2; k <= CAND_CAP; k <<= 1) {
        for (int j = k >> 1; j > 0; j >>= 1) {
            for (int t = threadIdx.x; t < CAND_CAP / 2; t += 1024) {
                const int i = ((t & ~(j - 1)) << 1) | (t & (j - 1));
                const int p = i | j;
                const uint64_t a = key[i], bb = key[p];
                const bool up = ((i & k) == 0);
                if ((a < bb) == up) { key[i] = bb; key[p] = a; }
            }
            __syncthreads();
        }
    }
    for (int r = threadIdx.x; r < K_PRE; r += 1024) {
        const uint32_t n = ~((uint32_t)key[r]);
        const float4 a = anch[(size_t)b * NN + n];
        const float4 d = bbox[(size_t)b * NN + n];
        float h = a.z - a.x, w = a.w - a.y;
        const float cy0 = a.x + 0.5f * h + d.x * 0.1f * h;
        const float cx0 = a.y + 0.5f * w + d.y * 0.1f * w;
        h = h * expf(d.z * 0.2f);
        w = w * expf(d.w * 0.2f);
        float4 o;
        o.x = fminf(fmaxf(cy0 - 0.5f * h, 0.0f), 1.0f);
        o.y = fminf(fmaxf(cx0 - 0.5f * w, 0.0f), 1.0f);
        o.z = fminf(fmaxf(cy0 + 0.5f * h, 0.0f), 1.0f);
        o.w = fminf(fmaxf(cx0 + 0.5f * w, 0.0f), 1.0f);
        boxes[(size_t)b * K_PRE + r] = o;
    }
}

__global__ __launch_bounds__(256) void k_matrix(const float4* __restrict__ boxes,
                                                uint32_t* __restrict__ mask) {
    const int blk = blockIdx.x;
    const int b = blk >> 10;
    const int tile = blk & 1023;
    const int ti = tile >> 5, tj = tile & 31;
    __shared__ float4 rb[64], cb[64];
    __shared__ uint32_t wbits[128];
    const float4* bx = boxes + (size_t)b * K_PRE;
    const int t = threadIdx.x;
    if (t < 64) rb[t] = bx[ti * 64 + t];
    else if (t < 128) cb[t - 64] = bx[tj * 64 + (t - 64)];
    if (t < 128) wbits[t] = 0;
    __syncthreads();
    const int r = t >> 2;
    const int cq = t & 3;
    const float4 a = rb[r];
    const float areaA = (a.z - a.x) * (a.w - a.y);
    uint32_t bits = 0;
#pragma unroll
    for (int jj = 0; jj < 16; ++jj) {
        const float4 cc = cb[cq * 16 + jj];
        const float yy1 = fmaxf(a.x, cc.x), xx1 = fmaxf(a.y, cc.y);
        const float yy2 = fminf(a.z, cc.z), xx2 = fminf(a.w, cc.w);
        const float inter = fmaxf(yy2 - yy1, 0.0f) * fmaxf(xx2 - xx1, 0.0f);
        const float areaC = (cc.z - cc.x) * (cc.w - cc.y);
        const float uni = fmaxf(areaA + areaC - inter, 1e-8f);
        if (inter / uni > NMS_THR) bits |= (1u << jj);
    }
    atomicOr(&wbits[r * 2 + (cq >> 1)], bits << ((cq & 1) * 16));
    __syncthreads();
    if (t < 128) {
        const int rr = t >> 1, ww = t & 1;
        mask[((size_t)b * PREFIX + ti * 64 + rr) * 64 + tj * 2 + ww] = wbits[rr * 2 + ww];
    }
}

// Greedy NMS bit-scan over the 2048x2048 suppression matrix.
__global__ __launch_bounds__(256) void k_greedy(const uint32_t* __restrict__ mask,
                                                uint32_t* meta, uint32_t* __restrict__ kept_idx) {
    __shared__ uint32_t lbuf[2][256 * 64];   // 2 x 64 KB
    __shared__ uint32_t skept[8];
    const int b = blockIdx.x;
    const int lane = threadIdx.x & 63;
    const int wave = threadIdx.x >> 6;
    const uint32_t* mrow = mask + (size_t)b * PREFIX * 64;

    {
        const uint4* s4 = (const uint4*)mrow;
        uint4* d4 = (uint4*)lbuf[0];
        for (int idx = threadIdx.x; idx < 4096; idx += 256) d4[idx] = s4[idx];
    }
    __syncthreads();

    uint32_t supp = 0;   // lane l: suppression bits for columns [32l, 32l+32)
    uint32_t kept = 0;

    for (int c = 0; c < PREFIX / 256; ++c) {
        if (wave > 0) {
            if (c + 1 < PREFIX / 256) {
                const uint4* s4 = (const uint4*)(mrow + (size_t)(c + 1) * 256 * 64);
                uint4* d4 = (uint4*)lbuf[(c + 1) & 1];
                for (int idx = threadIdx.x - 64; idx < 4096; idx += 192) d4[idx] = s4[idx];
            }
        } else {
            const uint32_t* L = lbuf[c & 1];
            for (int g = 0; g < 8; ++g) {
                if (kept >= NPROP) break;
                const int grow = c * 256 + g * 32;
                const int w = grow >> 5;
                uint32_t rbuf[32];
#pragma unroll
                for (int q = 0; q < 32; ++q) rbuf[q] = L[(g * 32 + q) * 64 + lane];
                uint32_t sw = __builtin_amdgcn_readlane(supp, w);
#pragma unroll
                for (int q = 0; q < 32; ++q) {
                    if (kept < NPROP && !((sw >> q) & 1u)) {
                        if (lane == 0) kept_idx[(size_t)b * NPROP + kept] = (uint32_t)(grow + q);
                        supp |= rbuf[q];
                        sw |= __builtin_amdgcn_readlane(rbuf[q], w);
                        ++kept;
                    }
                }
            }
            if (lane == 0) skept[c] = kept;
        }
        __syncthreads();
        if (skept[c] >= NPROP) break;
    }
    if (wave == 0 && lane == 0) meta[MT_KEPT + b] = kept;
}

__global__ __launch_bounds__(1024) void k_finish(const float4* __restrict__ boxes,
        uint32_t* meta, uint32_t* kept_idx, float4* __restrict__ out) {
    const int b = blockIdx.x;
    const float4* bx = boxes + (size_t)b * K_PRE;
    __shared__ float4 kb[NPROP];
    __shared__ uint32_t sflag;
    uint32_t kept = meta[MT_KEPT + b];
    if (kept < NPROP) {
        for (uint32_t k = threadIdx.x; k < kept; k += 1024)
            kb[k] = bx[kept_idx[(size_t)b * NPROP + k]];
        __syncthreads();
        for (int i = PREFIX; i < K_PRE && kept < NPROP; ++i) {
            if (threadIdx.x == 0) sflag = 0;
            __syncthreads();
            const float4 c = bx[i];
            const float areaC = (c.z - c.x) * (c.w - c.y);
            bool sup = false;
            for (uint32_t k = threadIdx.x; k < kept; k += 1024) {
                const float4 a = kb[k];
                const float yy1 = fmaxf(c.x, a.x), xx1 = fmaxf(c.y, a.y);
                const float yy2 = fminf(c.z, a.z), xx2 = fminf(c.w, a.w);
                const float inter = fmaxf(yy2 - yy1, 0.0f) * fmaxf(xx2 - xx1, 0.0f);
                const float areaA = (a.z - a.x) * (a.w - a.y);
                const float uni = fmaxf(areaC + areaA - inter, 1e-8f);
                if (inter / uni > NMS_THR) { sup = true; break; }
            }
            if (sup) atomicOr(&sflag, 1u);
            __syncthreads();
            if (sflag == 0) {
                if (threadIdx.x == 0) {
                    kept_idx[(size_t)b * NPROP + kept] = (uint32_t)i;
                    kb[kept] = c;
                }
                ++kept;
            }
            __syncthreads();
        }
        if (threadIdx.x == 0) meta[MT_KEPT + b] = kept;
    }
    __syncthreads();
    for (uint32_t k = threadIdx.x; k < NPROP; k += 1024) {
        float4 v = make_float4(0.f, 0.f, 0.f, 0.f);
        if (k < kept) v = bx[kept_idx[(size_t)b * NPROP + k]];
        out[(size_t)b * NPROP + k] = v;
    }
}

extern "C" void kernel_launch(void* const* d_in, const int* in_sizes, int n_in,
                              void* d_out, int out_size, void* d_ws, size_t ws_size,
                              hipStream_t stream) {
    const float4* probs4 = (const float4*)d_in[0];
    const float4* bbox   = (const float4*)d_in[1];
    const float4* anch   = (const float4*)d_in[2];
    char* ws = (char*)d_ws;
    if (ws_size < (size_t)WS_NEED) return;
    uint32_t* hist1 = (uint32_t*)(ws + HIST1_OFF);
    uint32_t* hist2 = (uint32_t*)(ws + HIST2_OFF);
    uint32_t* meta  = (uint32_t*)(ws + META_OFF);
    uint64_t* cand  = (uint64_t*)(ws + CAND_OFF);
    float4*   boxes = (float4*)(ws + BOXES_OFF);
    uint32_t* mask  = (uint32_t*)(ws + MASK_OFF);
    uint32_t* kidx  = (uint32_t*)(ws + KIDX_OFF);

    k_zero<<<dim3((BATCH * (NB1 + NB2) + 255) / 256), dim3(256), 0, stream>>>(hist1);
    k_hist<<<dim3(512), dim3(256), 0, stream>>>(probs4, hist1);
    k_thresh<<<dim3(BATCH), dim3(256), 0, stream>>>(hist1, meta);
    k_hist2<<<dim3(2048), dim3(256), 0, stream>>>(probs4, meta, hist2);
    k_thresh2<<<dim3(BATCH), dim3(256), 0, stream>>>(hist2, meta);
    k_compact<<<dim3(2048), dim3(256), 0, stream>>>(probs4, meta, meta, cand);
    k_sortdecode<<<dim3(BATCH), dim3(1024), 0, stream>>>(cand, meta, bbox, anch, boxes);
    k_matrix<<<dim3(BATCH * 1024), dim3(256), 0, stream>>>(boxes, mask);
    k_greedy<<<dim3(BATCH), dim3(256), 0, stream>>>(mask, meta, kidx);
    k_finish<<<dim3(BATCH), dim3(1024), 0, stream>>>(boxes, meta, kidx, (float4*)d_out);
}